// Round 8
// baseline (236.945 us; speedup 1.0000x reference)
//
#include <hip/hip_runtime.h>

#define NODES 100000
#define KNN 6

typedef unsigned short u16t;
typedef __attribute__((ext_vector_type(8))) short bf16x8;
typedef __attribute__((ext_vector_type(4))) float f32x4;
union U16 { uint4 u; bf16x8 b; };

__device__ inline f32x4 mfma16(bf16x8 a, bf16x8 b, f32x4 c) {
    return __builtin_amdgcn_mfma_f32_16x16x32_bf16(a, b, c, 0, 0, 0);
}
// pack top-16 bits of two fp32 words (u0 -> low half, u1 -> high half)
__device__ inline unsigned top2(unsigned u1, unsigned u0) {
    return __builtin_amdgcn_perm(u1, u0, 0x07060302u);
}
__device__ inline u16t bf16_rn(float x) {
    unsigned u = __float_as_uint(x);
    return (u16t)((u + 0x7FFF + ((u >> 16) & 1)) >> 16);
}
__device__ inline float bf16_f(u16t h) {
    return __uint_as_float(((unsigned)h) << 16);
}
// truncation split into hi/lo bf16 planes
__device__ inline void split_store(u16t* hp, u16t* lp, float v) {
    const unsigned u = __float_as_uint(v);
    *hp = (u16t)(u >> 16);
    const float hif = __uint_as_float(u & 0xFFFF0000u);
    *lp = (u16t)(__float_as_uint(v - hif) >> 16);
}
constexpr int cdiv(int a, int b) { return (a + b - 1) / b; }

// ---------------------------------------------------------------------------
// Weight prep: W[CIN_][N_] fp32 -> MFMA A-operand fragments (hi/lo bf16).
// Fragment (tile t, k-tile kt): elem[n = t*16 + (lane&15)][k = kt*32 + (lane>>4)*8 + j]
template <int CIN_, int N_>
__device__ void prep_dev(const float* __restrict__ W,
                         uint4* __restrict__ fh, uint4* __restrict__ fl, int idx) {
    constexpr int KT = (CIN_ + 31) / 32;
    constexpr int NTt = N_ / 16;
    if (idx >= NTt * KT * 64) return;
    const int lane = idx & 63;
    const int fk = idx >> 6;
    const int kt = fk % KT, t = fk / KT;
    const int n = t * 16 + (lane & 15);
    const int kbase = kt * 32 + (lane >> 4) * 8;
    unsigned h[4], l[4];
    for (int p = 0; p < 4; p++) {
        u16t hh[2], ll[2];
        for (int q = 0; q < 2; q++) {
            const int c = kbase + 2 * p + q;
            const float w = (c < CIN_) ? W[(size_t)c * N_ + n] : 0.f;
            const u16t hi = bf16_rn(w);
            hh[q] = hi;
            ll[q] = bf16_rn(w - bf16_f(hi));
        }
        h[p] = (unsigned)hh[0] | ((unsigned)hh[1] << 16);
        l[p] = (unsigned)ll[0] | ((unsigned)ll[1] << 16);
    }
    fh[idx] = make_uint4(h[0], h[1], h[2], h[3]);
    fl[idx] = make_uint4(l[0], l[1], l[2], l[3]);
}

__global__ void prep_all(const float* W1a, const float* W1b,
                         const float* W2a, const float* W2b,
                         const float* W3a, const float* W3b, uint4* wf) {
    const int b = blockIdx.x, t = threadIdx.x;
    if (b == 0)      prep_dev<6, 32>(W1a, wf + 0, wf + 128, t);
    else if (b == 1) prep_dev<32, 32>(W1b, wf + 256, wf + 384, t);
    else if (b < 4)  prep_dev<35, 64>(W2a, wf + 512, wf + 1024, (b - 2) * 256 + t);
    else if (b < 6)  prep_dev<64, 64>(W2b, wf + 1536, wf + 2048, (b - 4) * 256 + t);
    else if (b < 12) prep_dev<67, 128>(W3a, wf + 2560, wf + 4096, (b - 6) * 256 + t);
    else             prep_dev<128, 128>(W3b, wf + 5632, wf + 7680, (b - 12) * 256 + t);
}

// ---------------------------------------------------------------------------
// MFMA PointNetConv layer body. Features as separate hi/lo bf16 planes.
// CX==3: layer-1 mode (features = pos, staged directly; no x-gather).
// GEMM1: A = weights (regs, fully preloaded), B = data (LDS)  rows=channels, cols=edges
// GEMM2: A = data (LDS), B = weights (regs, preloaded in the GEMM1->GEMM2 gap)
//
// GEMM2 slot permutation (no padding; E = 48*g tiles of 16):
//   slot s (tile m, w = s&15, quad q = w>>2, reg r = w&3) maps to
//   edge = node*6 + i,  node = (m/3)*8 + 2q + (r>>1),  i = (m%3)*2 + (r&1).
// A node's 6 edges live in ONE lane across the m-triple's reg-pairs ->
// segment max is 6 in-lane fmax, no shuffles, no predication.
template <int CX, int H, int NWAVE, int NB, bool OUTP>
__device__ __forceinline__ void pnconv_body(
    const u16t* __restrict__ xh, const u16t* __restrict__ xl,
    const float* __restrict__ pos, const int* __restrict__ ei,
    const uint4* __restrict__ wfa_hi, const uint4* __restrict__ wfa_lo,
    const float* __restrict__ ba,
    const uint4* __restrict__ wfb_hi, const uint4* __restrict__ wfb_lo,
    const float* __restrict__ bb,
    float* __restrict__ outf, u16t* __restrict__ oh, u16t* __restrict__ ol)
{
    constexpr int NTH = NWAVE * 64;
    constexpr int CIN = CX + 3;
    constexpr int K1T = (CIN + 31) / 32;
    constexpr int K2T = H / 32;
    constexpr int NW = (H / 16) / NWAVE;     // channel tiles per wave
    constexpr int E = NB * KNN;
    constexpr int MT1 = E / 16;              // edge tiles (GEMM1 N)
    constexpr int MT2 = E / 16;              // slot tiles (GEMM2 M), unpadded
    constexpr int K1P = K1T * 32 + 8;        // ushort row strides (16B aligned)
    constexpr int K2P = K2T * 32 + 8;
    constexpr int APL = E * K1P;
    constexpr int HPL = E * K2P;
    constexpr int SM = (2 * APL > 2 * HPL) ? 2 * APL : 2 * HPL;
    static_assert(E % 48 == 0, "tile shape");
    static_assert(MT2 % 3 == 0, "slot perm needs m-triples");

    __shared__ __align__(16) u16t smem[SM];

    const int tid = threadIdx.x;
    const int lane = tid & 63, wv = tid >> 6;
    const int l15 = lane & 15, quad = lane >> 4;
    const int node0 = blockIdx.x * NB;
    const long e0 = (long)node0 * KNN;

    // ---- prefetch all gather indices into registers (no LDS, no barrier)
    constexpr int C8 = (CX % 8 == 0) ? CX / 8 : 1;
    constexpr int NGX = (CX % 8 == 0) ? cdiv(E * C8, NTH) : 1;
    constexpr int NGP = cdiv(E * 3, NTH);
    int sx_[NGX], sp_[NGP];
    if constexpr (CX % 8 == 0) {
#pragma unroll
        for (int k = 0; k < NGX; k++) {
            const int i = tid + k * NTH;
            sx_[k] = ei[e0 + ((i < E * C8) ? i / C8 : 0)];
        }
    }
#pragma unroll
    for (int k = 0; k < NGP; k++) {
        const int i = tid + k * NTH;
        sp_[k] = ei[e0 + ((i < E * 3) ? i / 3 : 0)];
    }

    // ---- GEMM1 weight fragments: full preload (latency hidden behind staging)
    U16 wah[NW][K1T], wal[NW][K1T];
#pragma unroll
    for (int t = 0; t < NW; t++)
#pragma unroll
        for (int kt = 0; kt < K1T; kt++) {
            const int fi = ((wv * NW + t) * K1T + kt) * 64 + lane;
            wah[t][kt].u = wfa_hi[fi];
            wal[t][kt].u = wfa_lo[fi];
        }

    // ---- stage feature planes into LDS (chunk-rotated writes)
    if constexpr (CX % 8 == 0) {
#pragma unroll
        for (int k = 0; k < NGX; k++) {
            const int i = tid + k * NTH;
            if (i < E * C8) {
                const int e = i / C8, c0 = i % C8;
                const int c = (c0 + e) & (C8 - 1);
                const size_t sb = (size_t)sx_[k] * CX + c * 8;
                *(uint4*)&smem[e * K1P + c * 8] = *(const uint4*)&xh[sb];
                *(uint4*)&smem[APL + e * K1P + c * 8] = *(const uint4*)&xl[sb];
            }
        }
    }
#pragma unroll
    for (int k = 0; k < NGP; k++) {
        const int i = tid + k * NTH;
        if (i < E * 3) {
            const int e = i / 3, d = i - 3 * (i / 3);
            const int s = sp_[k], nd = node0 + e / KNN;
            const float sp = pos[3 * s + d];
            if constexpr (CX == 3)
                split_store(&smem[e * K1P + d], &smem[APL + e * K1P + d], sp);
            split_store(&smem[e * K1P + CX + d], &smem[APL + e * K1P + CX + d],
                        sp - pos[3 * nd + d]);
        }
    }
    // zero the K padding
    constexpr int PADA = (CIN + 7) & ~7;
    constexpr int NU4 = (K1P - PADA) / 8;
    for (int i = tid; i < 2 * E; i += NTH) {
        const int pl = (i >= E) ? 1 : 0;
        const int e = i - pl * E;
        u16t* row = &smem[pl * APL + e * K1P];
        for (int k = CIN; k < PADA; k++) row[k] = 0;
        for (int j = 0; j < NU4; j++) *(uint4*)&row[PADA + j * 8] = make_uint4(0, 0, 0, 0);
    }
    __syncthreads();

    // ---- GEMM1: D[channel][edge] = W1^T * A^T (3-term bf16 split)
    f32x4 acc1[NW][MT1];
#pragma unroll
    for (int t = 0; t < NW; t++)
#pragma unroll
        for (int m = 0; m < MT1; m++) acc1[t][m] = (f32x4){0.f, 0.f, 0.f, 0.f};

#pragma unroll
    for (int kt = 0; kt < K1T; kt++) {
#pragma unroll
        for (int m = 0; m < MT1; m++) {
            const u16t* p = &smem[(m * 16 + l15) * K1P + kt * 32 + quad * 8];
            U16 dh, dl;
            dh.u = *(const uint4*)p;
            dl.u = *(const uint4*)(p + APL);
#pragma unroll
            for (int t = 0; t < NW; t++) {
                acc1[t][m] = mfma16(wah[t][kt].b, dh.b, acc1[t][m]);
                acc1[t][m] = mfma16(wah[t][kt].b, dl.b, acc1[t][m]);
                acc1[t][m] = mfma16(wal[t][kt].b, dh.b, acc1[t][m]);
            }
        }
    }

    // GEMM2 weights: full preload issued now; first use is 2 barriers away
    U16 wbh[NW][K2T], wbl[NW][K2T];
#pragma unroll
    for (int t = 0; t < NW; t++)
#pragma unroll
        for (int kt = 0; kt < K2T; kt++) {
            const int fi = ((wv * NW + t) * K2T + kt) * 64 + lane;
            wbh[t][kt].u = wfb_hi[fi];
            wbl[t][kt].u = wfb_lo[fi];
        }
    __syncthreads();   // all A reads done; smem becomes Hp planes

    // ---- bias + relu + trunc-split, write Hp planes
#pragma unroll
    for (int t = 0; t < NW; t++) {
        const int khb = (wv * NW + t) * 16 + quad * 4;
        const float4 bs = *(const float4*)&ba[khb];
#pragma unroll
        for (int m = 0; m < MT1; m++) {
            const float v0 = fmaxf(acc1[t][m][0] + bs.x, 0.f);
            const float v1 = fmaxf(acc1[t][m][1] + bs.y, 0.f);
            const float v2 = fmaxf(acc1[t][m][2] + bs.z, 0.f);
            const float v3 = fmaxf(acc1[t][m][3] + bs.w, 0.f);
            const unsigned u0 = __float_as_uint(v0), u1 = __float_as_uint(v1);
            const unsigned u2 = __float_as_uint(v2), u3 = __float_as_uint(v3);
            uint2 hw, lw;
            hw.x = top2(u1, u0);
            hw.y = top2(u3, u2);
            const float l0 = v0 - __uint_as_float(u0 & 0xFFFF0000u);
            const float l1 = v1 - __uint_as_float(u1 & 0xFFFF0000u);
            const float l2 = v2 - __uint_as_float(u2 & 0xFFFF0000u);
            const float l3 = v3 - __uint_as_float(u3 & 0xFFFF0000u);
            lw.x = top2(__float_as_uint(l1), __float_as_uint(l0));
            lw.y = top2(__float_as_uint(l3), __float_as_uint(l2));
            u16t* wp = &smem[(m * 16 + l15) * K2P + khb];
            *(uint2*)wp = hw;
            *(uint2*)(wp + HPL) = lw;
        }
    }
    __syncthreads();

    // ---- GEMM2 (swapped): D[slot][channel] = Hp * W2
    int eaddr[MT2];
#pragma unroll
    for (int m = 0; m < MT2; m++) {
        const int nd_s = (m / 3) * 8 + 2 * (l15 >> 2) + ((l15 >> 1) & 1);
        const int i_s = (m % 3) * 2 + (l15 & 1);
        eaddr[m] = (nd_s * KNN + i_s) * K2P + quad * 8;
    }

    f32x4 acc2[NW][MT2];
#pragma unroll
    for (int t = 0; t < NW; t++)
#pragma unroll
        for (int m = 0; m < MT2; m++) acc2[t][m] = (f32x4){0.f, 0.f, 0.f, 0.f};

#pragma unroll
    for (int kt = 0; kt < K2T; kt++) {
#pragma unroll
        for (int m = 0; m < MT2; m++) {
            const u16t* p = &smem[eaddr[m] + kt * 32];
            U16 dh, dl;
            dh.u = *(const uint4*)p;
            dl.u = *(const uint4*)(p + HPL);
#pragma unroll
            for (int t = 0; t < NW; t++) {
                acc2[t][m] = mfma16(dh.b, wbh[t][kt].b, acc2[t][m]);
                acc2[t][m] = mfma16(dh.b, wbl[t][kt].b, acc2[t][m]);
                acc2[t][m] = mfma16(dl.b, wbh[t][kt].b, acc2[t][m]);
            }
        }
    }

    // ---- segment max: fully in-lane (slot perm), 2 nodes per lane per m-triple
#pragma unroll
    for (int t = 0; t < NW; t++) {
        const int nb = (wv * NW + t) * 16;
        const float bias = bb[nb + l15];
#pragma unroll
        for (int g = 0; g < MT2 / 3; g++) {
#pragma unroll
            for (int rp = 0; rp < 2; rp++) {
                float v = fmaxf(
                    fmaxf(fmaxf(acc2[t][3 * g + 0][2 * rp], acc2[t][3 * g + 0][2 * rp + 1]),
                          fmaxf(acc2[t][3 * g + 1][2 * rp], acc2[t][3 * g + 1][2 * rp + 1])),
                    fmaxf(acc2[t][3 * g + 2][2 * rp], acc2[t][3 * g + 2][2 * rp + 1]));
                v = fmaxf(v + bias, 0.f);
                const int node = node0 + g * 8 + 2 * quad + rp;
                const size_t oidx = (size_t)node * H + nb + l15;
                if constexpr (OUTP) {
                    split_store(&oh[oidx], &ol[oidx], v);
                } else {
                    outf[oidx] = v;
                }
            }
        }
    }
}

// ---- distinct kernel names per layer (profiling clarity) ----
__global__ __launch_bounds__(128, 4) void pn_l1(
    const float* __restrict__ pos, const int* __restrict__ ei,
    const uint4* __restrict__ wf, const float* __restrict__ b1a,
    const float* __restrict__ b1b, u16t* __restrict__ oh, u16t* __restrict__ ol) {
    pnconv_body<3, 32, 2, 16, true>(nullptr, nullptr, pos, ei,
        wf + 0, wf + 128, b1a, wf + 256, wf + 384, b1b, nullptr, oh, ol);
}
__global__ __launch_bounds__(256, 4) void pn_l2(
    const u16t* __restrict__ xh, const u16t* __restrict__ xl,
    const float* __restrict__ pos, const int* __restrict__ ei,
    const uint4* __restrict__ wf, const float* __restrict__ b2a,
    const float* __restrict__ b2b, u16t* __restrict__ oh, u16t* __restrict__ ol) {
    pnconv_body<32, 64, 4, 16, true>(xh, xl, pos, ei,
        wf + 512, wf + 1024, b2a, wf + 1536, wf + 2048, b2b, nullptr, oh, ol);
}
__global__ __launch_bounds__(256, 4) void pn_l3(
    const u16t* __restrict__ xh, const u16t* __restrict__ xl,
    const float* __restrict__ pos, const int* __restrict__ ei,
    const uint4* __restrict__ wf, const float* __restrict__ b3a,
    const float* __restrict__ b3b, float* __restrict__ outf) {
    pnconv_body<64, 128, 4, 8, false>(xh, xl, pos, ei,
        wf + 2560, wf + 4096, b3a, wf + 5632, wf + 7680, b3b, outf, nullptr, nullptr);
}

// ---------------------------------------------------------------------------
extern "C" void kernel_launch(void* const* d_in, const int* in_sizes, int n_in,
                              void* d_out, int out_size, void* d_ws, size_t ws_size,
                              hipStream_t stream) {
    const float* pos = (const float*)d_in[0];
    const int* ei = (const int*)d_in[1];
    const float* W1a = (const float*)d_in[2];
    const float* b1a = (const float*)d_in[3];
    const float* W1b = (const float*)d_in[4];
    const float* b1b = (const float*)d_in[5];
    const float* W2a = (const float*)d_in[6];
    const float* b2a = (const float*)d_in[7];
    const float* W2b = (const float*)d_in[8];
    const float* b2b = (const float*)d_in[9];
    const float* W3a = (const float*)d_in[10];
    const float* b3a = (const float*)d_in[11];
    const float* W3b = (const float*)d_in[12];
    const float* b3b = (const float*)d_in[13];

    u16t* h1h = (u16t*)d_ws;                       // [NODES][32] hi plane
    u16t* h1l = h1h + (size_t)NODES * 32;          // [NODES][32] lo plane
    u16t* h2h = h1l + (size_t)NODES * 32;          // [NODES][64] hi plane
    u16t* h2l = h2h + (size_t)NODES * 64;          // [NODES][64] lo plane
    uint4* wf = (uint4*)(h2l + (size_t)NODES * 64);
    // fragment uint4 offsets:
    //   W1a h/l @0/128, W1b @256/384, W2a @512/1024, W2b @1536/2048,
    //   W3a @2560/4096 (len 1536), W3b @5632/7680 (len 2048); end 9728

    prep_all<<<20, 256, 0, stream>>>(W1a, W1b, W2a, W2b, W3a, W3b, wf);
    pn_l1<<<NODES / 16, 128, 0, stream>>>(pos, ei, wf, b1a, b1b, h1h, h1l);
    pn_l2<<<NODES / 16, 256, 0, stream>>>(h1h, h1l, pos, ei, wf, b2a, b2b, h2h, h2l);
    pn_l3<<<NODES / 8, 256, 0, stream>>>(h2h, h2l, pos, ei, wf, b3a, b3b, (float*)d_out);
}

// Round 9
// 236.012 us; speedup vs baseline: 1.0040x; 1.0040x over previous
//
#include <hip/hip_runtime.h>

#define NODES 100000
#define KNN 6

typedef unsigned short u16t;
typedef __attribute__((ext_vector_type(8))) short bf16x8;
typedef __attribute__((ext_vector_type(4))) float f32x4;
union U16 { uint4 u; bf16x8 b; };

__device__ inline f32x4 mfma16(bf16x8 a, bf16x8 b, f32x4 c) {
    return __builtin_amdgcn_mfma_f32_16x16x32_bf16(a, b, c, 0, 0, 0);
}
// pack top-16 bits of two fp32 words (u0 -> low half, u1 -> high half)
__device__ inline unsigned top2(unsigned u1, unsigned u0) {
    return __builtin_amdgcn_perm(u1, u0, 0x07060302u);
}
__device__ inline u16t bf16_rn(float x) {
    unsigned u = __float_as_uint(x);
    return (u16t)((u + 0x7FFF + ((u >> 16) & 1)) >> 16);
}
__device__ inline float bf16_f(u16t h) {
    return __uint_as_float(((unsigned)h) << 16);
}
// truncation split into hi/lo bf16 planes
__device__ inline void split_store(u16t* hp, u16t* lp, float v) {
    const unsigned u = __float_as_uint(v);
    *hp = (u16t)(u >> 16);
    const float hif = __uint_as_float(u & 0xFFFF0000u);
    *lp = (u16t)(__float_as_uint(v - hif) >> 16);
}
constexpr int cdiv(int a, int b) { return (a + b - 1) / b; }

// ---------------------------------------------------------------------------
// Weight prep: W[CIN_][N_] fp32 -> MFMA A-operand fragments (hi/lo bf16).
// Fragment (tile t, k-tile kt): elem[n = t*16 + (lane&15)][k = kt*32 + (lane>>4)*8 + j]
template <int CIN_, int N_>
__device__ void prep_dev(const float* __restrict__ W,
                         uint4* __restrict__ fh, uint4* __restrict__ fl, int idx) {
    constexpr int KT = (CIN_ + 31) / 32;
    constexpr int NTt = N_ / 16;
    if (idx >= NTt * KT * 64) return;
    const int lane = idx & 63;
    const int fk = idx >> 6;
    const int kt = fk % KT, t = fk / KT;
    const int n = t * 16 + (lane & 15);
    const int kbase = kt * 32 + (lane >> 4) * 8;
    unsigned h[4], l[4];
    for (int p = 0; p < 4; p++) {
        u16t hh[2], ll[2];
        for (int q = 0; q < 2; q++) {
            const int c = kbase + 2 * p + q;
            const float w = (c < CIN_) ? W[(size_t)c * N_ + n] : 0.f;
            const u16t hi = bf16_rn(w);
            hh[q] = hi;
            ll[q] = bf16_rn(w - bf16_f(hi));
        }
        h[p] = (unsigned)hh[0] | ((unsigned)hh[1] << 16);
        l[p] = (unsigned)ll[0] | ((unsigned)ll[1] << 16);
    }
    fh[idx] = make_uint4(h[0], h[1], h[2], h[3]);
    fl[idx] = make_uint4(l[0], l[1], l[2], l[3]);
}

__global__ void prep_all(const float* W1a, const float* W1b,
                         const float* W2a, const float* W2b,
                         const float* W3a, const float* W3b, uint4* wf) {
    const int b = blockIdx.x, t = threadIdx.x;
    if (b == 0)      prep_dev<6, 32>(W1a, wf + 0, wf + 128, t);
    else if (b == 1) prep_dev<32, 32>(W1b, wf + 256, wf + 384, t);
    else if (b < 4)  prep_dev<35, 64>(W2a, wf + 512, wf + 1024, (b - 2) * 256 + t);
    else if (b < 6)  prep_dev<64, 64>(W2b, wf + 1536, wf + 2048, (b - 4) * 256 + t);
    else if (b < 12) prep_dev<67, 128>(W3a, wf + 2560, wf + 4096, (b - 6) * 256 + t);
    else             prep_dev<128, 128>(W3b, wf + 5632, wf + 7680, (b - 12) * 256 + t);
}

// ---------------------------------------------------------------------------
// MFMA PointNetConv layer body. Features as separate hi/lo bf16 planes.
// CX==3: layer-1 mode (features = pos, staged directly; no x-gather).
// GEMM1: A = weights (regs, kt-streamed ping-pong), B = data (LDS)
// GEMM2: A = data (LDS), B = weights (regs, kt-streamed ping-pong)
// 2-slot streaming is deliberate: full preload costs ~24 regs -> occupancy
// 58%->41% -> net regression (measured R8). Keep combined VGPR+AGPR < ~112.
//
// GEMM2 slot permutation (no padding; E = 48*g tiles of 16):
//   slot s (tile m, w = s&15, quad q = w>>2, reg r = w&3) maps to
//   edge = node*6 + i,  node = (m/3)*8 + 2q + (r>>1),  i = (m%3)*2 + (r&1).
// A node's 6 edges live in ONE lane across the m-triple's reg-pairs ->
// segment max is 6 in-lane fmax, no shuffles, no predication.
template <int CX, int H, int NWAVE, int NB, bool OUTP>
__device__ __forceinline__ void pnconv_body(
    const u16t* __restrict__ xh, const u16t* __restrict__ xl,
    const float* __restrict__ pos, const int* __restrict__ ei,
    const uint4* __restrict__ wfa_hi, const uint4* __restrict__ wfa_lo,
    const float* __restrict__ ba,
    const uint4* __restrict__ wfb_hi, const uint4* __restrict__ wfb_lo,
    const float* __restrict__ bb,
    float* __restrict__ outf, u16t* __restrict__ oh, u16t* __restrict__ ol)
{
    constexpr int NTH = NWAVE * 64;
    constexpr int CIN = CX + 3;
    constexpr int K1T = (CIN + 31) / 32;
    constexpr int K2T = H / 32;
    constexpr int NW = (H / 16) / NWAVE;     // channel tiles per wave
    constexpr int E = NB * KNN;
    constexpr int MT1 = E / 16;              // edge tiles (GEMM1 N)
    constexpr int MT2 = E / 16;              // slot tiles (GEMM2 M), unpadded
    constexpr int K1P = K1T * 32 + 8;        // ushort row strides (16B aligned)
    constexpr int K2P = K2T * 32 + 8;
    constexpr int APL = E * K1P;
    constexpr int HPL = E * K2P;
    constexpr int SM = (2 * APL > 2 * HPL) ? 2 * APL : 2 * HPL;
    static_assert(E % 48 == 0, "tile shape");
    static_assert(MT2 % 3 == 0, "slot perm needs m-triples");

    __shared__ __align__(16) u16t smem[SM];

    const int tid = threadIdx.x;
    const int lane = tid & 63, wv = tid >> 6;
    const int l15 = lane & 15, quad = lane >> 4;
    const int node0 = blockIdx.x * NB;
    const long e0 = (long)node0 * KNN;

    // ---- prefetch all gather indices into registers (no LDS, no barrier)
    constexpr int C8 = (CX % 8 == 0) ? CX / 8 : 1;
    constexpr int NGX = (CX % 8 == 0) ? cdiv(E * C8, NTH) : 1;
    constexpr int NGP = cdiv(E * 3, NTH);
    int sx_[NGX], sp_[NGP];
    if constexpr (CX % 8 == 0) {
#pragma unroll
        for (int k = 0; k < NGX; k++) {
            const int i = tid + k * NTH;
            sx_[k] = ei[e0 + ((i < E * C8) ? i / C8 : 0)];
        }
    }
#pragma unroll
    for (int k = 0; k < NGP; k++) {
        const int i = tid + k * NTH;
        sp_[k] = ei[e0 + ((i < E * 3) ? i / 3 : 0)];
    }

    // ---- GEMM1 weights: kt=0 preload (ping-pong streamed in the loop)
    U16 wah[2][NW], wal[2][NW];
#pragma unroll
    for (int t = 0; t < NW; t++) {
        const int fi = ((wv * NW + t) * K1T) * 64 + lane;
        wah[0][t].u = wfa_hi[fi];
        wal[0][t].u = wfa_lo[fi];
    }

    // ---- stage feature planes into LDS (chunk-rotated writes)
    if constexpr (CX % 8 == 0) {
#pragma unroll
        for (int k = 0; k < NGX; k++) {
            const int i = tid + k * NTH;
            if (i < E * C8) {
                const int e = i / C8, c0 = i % C8;
                const int c = (c0 + e) & (C8 - 1);
                const size_t sb = (size_t)sx_[k] * CX + c * 8;
                *(uint4*)&smem[e * K1P + c * 8] = *(const uint4*)&xh[sb];
                *(uint4*)&smem[APL + e * K1P + c * 8] = *(const uint4*)&xl[sb];
            }
        }
    }
#pragma unroll
    for (int k = 0; k < NGP; k++) {
        const int i = tid + k * NTH;
        if (i < E * 3) {
            const int e = i / 3, d = i - 3 * (i / 3);
            const int s = sp_[k], nd = node0 + e / KNN;
            const float sp = pos[3 * s + d];
            if constexpr (CX == 3)
                split_store(&smem[e * K1P + d], &smem[APL + e * K1P + d], sp);
            split_store(&smem[e * K1P + CX + d], &smem[APL + e * K1P + CX + d],
                        sp - pos[3 * nd + d]);
        }
    }
    // zero the K padding
    constexpr int PADA = (CIN + 7) & ~7;
    constexpr int NU4 = (K1P - PADA) / 8;
    for (int i = tid; i < 2 * E; i += NTH) {
        const int pl = (i >= E) ? 1 : 0;
        const int e = i - pl * E;
        u16t* row = &smem[pl * APL + e * K1P];
        for (int k = CIN; k < PADA; k++) row[k] = 0;
        for (int j = 0; j < NU4; j++) *(uint4*)&row[PADA + j * 8] = make_uint4(0, 0, 0, 0);
    }
    __syncthreads();

    // ---- GEMM1: D[channel][edge] = W1^T * A^T (3-term bf16 split)
    f32x4 acc1[NW][MT1];
#pragma unroll
    for (int t = 0; t < NW; t++)
#pragma unroll
        for (int m = 0; m < MT1; m++) acc1[t][m] = (f32x4){0.f, 0.f, 0.f, 0.f};

#pragma unroll
    for (int kt = 0; kt < K1T; kt++) {
        const int cur = kt & 1, nxt = cur ^ 1;
        const int nkt = (kt + 1 < K1T) ? kt + 1 : kt;
#pragma unroll
        for (int t = 0; t < NW; t++) {      // prefetch next kt's weights
            const int fi = ((wv * NW + t) * K1T + nkt) * 64 + lane;
            wah[nxt][t].u = wfa_hi[fi];
            wal[nxt][t].u = wfa_lo[fi];
        }
#pragma unroll
        for (int m = 0; m < MT1; m++) {
            const u16t* p = &smem[(m * 16 + l15) * K1P + kt * 32 + quad * 8];
            U16 dh, dl;
            dh.u = *(const uint4*)p;
            dl.u = *(const uint4*)(p + APL);
#pragma unroll
            for (int t = 0; t < NW; t++) {
                acc1[t][m] = mfma16(wah[cur][t].b, dh.b, acc1[t][m]);
                acc1[t][m] = mfma16(wah[cur][t].b, dl.b, acc1[t][m]);
                acc1[t][m] = mfma16(wal[cur][t].b, dh.b, acc1[t][m]);
            }
        }
    }

    // GEMM2 weights: kt=0 preload (latency covered by epilogue + barrier)
    U16 wbh[2][NW], wbl[2][NW];
#pragma unroll
    for (int t = 0; t < NW; t++) {
        const int fi = ((wv * NW + t) * K2T) * 64 + lane;
        wbh[0][t].u = wfb_hi[fi];
        wbl[0][t].u = wfb_lo[fi];
    }
    __syncthreads();   // all A reads done; smem becomes Hp planes

    // ---- bias + relu + trunc-split, write Hp planes
#pragma unroll
    for (int t = 0; t < NW; t++) {
        const int khb = (wv * NW + t) * 16 + quad * 4;
        const float4 bs = *(const float4*)&ba[khb];
#pragma unroll
        for (int m = 0; m < MT1; m++) {
            const float v0 = fmaxf(acc1[t][m][0] + bs.x, 0.f);
            const float v1 = fmaxf(acc1[t][m][1] + bs.y, 0.f);
            const float v2 = fmaxf(acc1[t][m][2] + bs.z, 0.f);
            const float v3 = fmaxf(acc1[t][m][3] + bs.w, 0.f);
            const unsigned u0 = __float_as_uint(v0), u1 = __float_as_uint(v1);
            const unsigned u2 = __float_as_uint(v2), u3 = __float_as_uint(v3);
            uint2 hw, lw;
            hw.x = top2(u1, u0);
            hw.y = top2(u3, u2);
            const float l0 = v0 - __uint_as_float(u0 & 0xFFFF0000u);
            const float l1 = v1 - __uint_as_float(u1 & 0xFFFF0000u);
            const float l2 = v2 - __uint_as_float(u2 & 0xFFFF0000u);
            const float l3 = v3 - __uint_as_float(u3 & 0xFFFF0000u);
            lw.x = top2(__float_as_uint(l1), __float_as_uint(l0));
            lw.y = top2(__float_as_uint(l3), __float_as_uint(l2));
            u16t* wp = &smem[(m * 16 + l15) * K2P + khb];
            *(uint2*)wp = hw;
            *(uint2*)(wp + HPL) = lw;
        }
    }
    __syncthreads();

    // ---- GEMM2 (swapped): D[slot][channel] = Hp * W2, weights streamed per kt
    int eaddr[MT2];
#pragma unroll
    for (int m = 0; m < MT2; m++) {
        const int nd_s = (m / 3) * 8 + 2 * (l15 >> 2) + ((l15 >> 1) & 1);
        const int i_s = (m % 3) * 2 + (l15 & 1);
        eaddr[m] = (nd_s * KNN + i_s) * K2P + quad * 8;
    }

    f32x4 acc2[NW][MT2];
#pragma unroll
    for (int t = 0; t < NW; t++)
#pragma unroll
        for (int m = 0; m < MT2; m++) acc2[t][m] = (f32x4){0.f, 0.f, 0.f, 0.f};

#pragma unroll
    for (int kt = 0; kt < K2T; kt++) {
        const int cur = kt & 1, nxt = cur ^ 1;
        const int nkt = (kt + 1 < K2T) ? kt + 1 : kt;
#pragma unroll
        for (int t = 0; t < NW; t++) {
            const int fi = ((wv * NW + t) * K2T + nkt) * 64 + lane;
            wbh[nxt][t].u = wfb_hi[fi];
            wbl[nxt][t].u = wfb_lo[fi];
        }
#pragma unroll
        for (int m = 0; m < MT2; m++) {
            const u16t* p = &smem[eaddr[m] + kt * 32];
            U16 dh, dl;
            dh.u = *(const uint4*)p;
            dl.u = *(const uint4*)(p + HPL);
#pragma unroll
            for (int t = 0; t < NW; t++) {
                acc2[t][m] = mfma16(dh.b, wbh[cur][t].b, acc2[t][m]);
                acc2[t][m] = mfma16(dh.b, wbl[cur][t].b, acc2[t][m]);
                acc2[t][m] = mfma16(dl.b, wbh[cur][t].b, acc2[t][m]);
            }
        }
    }

    // ---- segment max: fully in-lane (slot perm), 2 nodes per lane per m-triple
#pragma unroll
    for (int t = 0; t < NW; t++) {
        const int nb = (wv * NW + t) * 16;
        const float bias = bb[nb + l15];
#pragma unroll
        for (int g = 0; g < MT2 / 3; g++) {
#pragma unroll
            for (int rp = 0; rp < 2; rp++) {
                float v = fmaxf(
                    fmaxf(fmaxf(acc2[t][3 * g + 0][2 * rp], acc2[t][3 * g + 0][2 * rp + 1]),
                          fmaxf(acc2[t][3 * g + 1][2 * rp], acc2[t][3 * g + 1][2 * rp + 1])),
                    fmaxf(acc2[t][3 * g + 2][2 * rp], acc2[t][3 * g + 2][2 * rp + 1]));
                v = fmaxf(v + bias, 0.f);
                const int node = node0 + g * 8 + 2 * quad + rp;
                const size_t oidx = (size_t)node * H + nb + l15;
                if constexpr (OUTP) {
                    split_store(&oh[oidx], &ol[oidx], v);
                } else {
                    outf[oidx] = v;
                }
            }
        }
    }
}

// ---- distinct kernel names per layer (profiling clarity) ----
__global__ __launch_bounds__(128, 4) void pn_l1(
    const float* __restrict__ pos, const int* __restrict__ ei,
    const uint4* __restrict__ wf, const float* __restrict__ b1a,
    const float* __restrict__ b1b, u16t* __restrict__ oh, u16t* __restrict__ ol) {
    pnconv_body<3, 32, 2, 16, true>(nullptr, nullptr, pos, ei,
        wf + 0, wf + 128, b1a, wf + 256, wf + 384, b1b, nullptr, oh, ol);
}
__global__ __launch_bounds__(256, 4) void pn_l2(
    const u16t* __restrict__ xh, const u16t* __restrict__ xl,
    const float* __restrict__ pos, const int* __restrict__ ei,
    const uint4* __restrict__ wf, const float* __restrict__ b2a,
    const float* __restrict__ b2b, u16t* __restrict__ oh, u16t* __restrict__ ol) {
    pnconv_body<32, 64, 4, 16, true>(xh, xl, pos, ei,
        wf + 512, wf + 1024, b2a, wf + 1536, wf + 2048, b2b, nullptr, oh, ol);
}
__global__ __launch_bounds__(256, 4) void pn_l3(
    const u16t* __restrict__ xh, const u16t* __restrict__ xl,
    const float* __restrict__ pos, const int* __restrict__ ei,
    const uint4* __restrict__ wf, const float* __restrict__ b3a,
    const float* __restrict__ b3b, float* __restrict__ outf) {
    pnconv_body<64, 128, 4, 8, false>(xh, xl, pos, ei,
        wf + 2560, wf + 4096, b3a, wf + 5632, wf + 7680, b3b, outf, nullptr, nullptr);
}

// ---------------------------------------------------------------------------
extern "C" void kernel_launch(void* const* d_in, const int* in_sizes, int n_in,
                              void* d_out, int out_size, void* d_ws, size_t ws_size,
                              hipStream_t stream) {
    const float* pos = (const float*)d_in[0];
    const int* ei = (const int*)d_in[1];
    const float* W1a = (const float*)d_in[2];
    const float* b1a = (const float*)d_in[3];
    const float* W1b = (const float*)d_in[4];
    const float* b1b = (const float*)d_in[5];
    const float* W2a = (const float*)d_in[6];
    const float* b2a = (const float*)d_in[7];
    const float* W2b = (const float*)d_in[8];
    const float* b2b = (const float*)d_in[9];
    const float* W3a = (const float*)d_in[10];
    const float* b3a = (const float*)d_in[11];
    const float* W3b = (const float*)d_in[12];
    const float* b3b = (const float*)d_in[13];

    u16t* h1h = (u16t*)d_ws;                       // [NODES][32] hi plane
    u16t* h1l = h1h + (size_t)NODES * 32;          // [NODES][32] lo plane
    u16t* h2h = h1l + (size_t)NODES * 32;          // [NODES][64] hi plane
    u16t* h2l = h2h + (size_t)NODES * 64;          // [NODES][64] lo plane
    uint4* wf = (uint4*)(h2l + (size_t)NODES * 64);
    // fragment uint4 offsets:
    //   W1a h/l @0/128, W1b @256/384, W2a @512/1024, W2b @1536/2048,
    //   W3a @2560/4096 (len 1536), W3b @5632/7680 (len 2048); end 9728

    prep_all<<<20, 256, 0, stream>>>(W1a, W1b, W2a, W2b, W3a, W3b, wf);
    pn_l1<<<NODES / 16, 128, 0, stream>>>(pos, ei, wf, b1a, b1b, h1h, h1l);
    pn_l2<<<NODES / 16, 256, 0, stream>>>(h1h, h1l, pos, ei, wf, b2a, b2b, h2h, h2l);
    pn_l3<<<NODES / 8, 256, 0, stream>>>(h2h, h2l, pos, ei, wf, b3a, b3b, (float*)d_out);
}